// Round 1
// baseline (530.088 us; speedup 1.0000x reference)
//
#include <hip/hip_runtime.h>

#define NB 8        // batches
#define NY 180      // render size (ky / y / x count)
#define NKX 91      // rfft half-width
#define NV 192      // volume dim
#define SCALEF (75.0f/16384.0f)   // 180^2/192^3 exactly

typedef unsigned long long ull;

__device__ __forceinline__ unsigned int enc_f(float v) {
    unsigned int u = __float_as_uint(v);
    return (u & 0x80000000u) ? ~u : (u | 0x80000000u);
}
__device__ __forceinline__ float dec_f(unsigned int u) {
    return __uint_as_float((u & 0x80000000u) ? (u & 0x7FFFFFFFu) : ~u);
}

// Kernel 1: per (b,kx) column — sample rotated plane, cross-spectrum, ky inverse DFT.
__global__ __launch_bounds__(192) void k_sample_colfft(
    const float* __restrict__ src, const float* __restrict__ rot,
    const float* __restrict__ ref, float* __restrict__ T)
{
    const int blk = blockIdx.x;          // b*NKX + kx
    const int b = blk / NKX, kx = blk - b * NKX;
    const int t = threadIdx.x;

    __shared__ float Gr[NY], Gi[NY];
    __shared__ float ctab[NY], stab[NY];

    if (t < NY) {
        double a = (double)t * (6.283185307179586476925286766559 / 180.0);
        ctab[t] = (float)cos(a);
        stab[t] = (float)sin(a);
    }

    if (t < NY) {
        // fftshift: output ky=t comes from sampled row i=(t+90)%180
        int i = t + 90; if (i >= NY) i -= NY;
        float xg = (float)kx / 96.0f;
        float yg = (float)(i - 90) / 96.0f;
        const float* R = rot + (size_t)b * 9;
        float p0 = xg * R[0] + yg * R[3];
        float p1 = xg * R[1] + yg * R[4];
        float p2 = xg * R[2] + yg * R[5];
        float fx = (p0 + 1.0f) * 0.5f * 191.0f;
        float fy = (p1 + 1.0f) * 0.5f * 191.0f;
        float fz = (p2 + 1.0f) * 0.5f * 191.0f;
        float x0 = floorf(fx), y0 = floorf(fy), z0 = floorf(fz);
        float wx = fx - x0, wy = fy - y0, wz = fz - z0;

        float s0 = 0.f, s1 = 0.f;
        const float* vb = src + (size_t)b * 2u * NV * NV * NV;
        #pragma unroll
        for (int dz = 0; dz < 2; ++dz) {
            float zi = z0 + (float)dz;
            float wzc = dz ? wz : 1.0f - wz;
            bool vz = (zi >= 0.f) && (zi < (float)NV);
            int zc = (int)fminf(fmaxf(zi, 0.f), (float)(NV - 1));
            #pragma unroll
            for (int dy = 0; dy < 2; ++dy) {
                float yi = y0 + (float)dy;
                float wyc = dy ? wy : 1.0f - wy;
                bool vy = (yi >= 0.f) && (yi < (float)NV);
                int yc = (int)fminf(fmaxf(yi, 0.f), (float)(NV - 1));
                #pragma unroll
                for (int dx = 0; dx < 2; ++dx) {
                    float xi = x0 + (float)dx;
                    float wxc = dx ? wx : 1.0f - wx;
                    bool vx = (xi >= 0.f) && (xi < (float)NV);
                    int xc = (int)fminf(fmaxf(xi, 0.f), (float)(NV - 1));
                    if (vz && vy && vx) {
                        float w = wzc * wyc * wxc;
                        size_t off = ((size_t)zc * NV + (size_t)yc) * NV + (size_t)xc;
                        s0 += vb[off] * w;
                        s1 += vb[(size_t)NV * NV * NV + off] * w;
                    }
                }
            }
        }
        s0 *= SCALEF; s1 *= SCALEF;

        // cross = s * conj(ref);  fold (w_kx * 2 / 180^2)
        const float* rp = ref + (((size_t)b * NY + (size_t)t) * NKX + (size_t)kx) * 2u;
        float rr = rp[0], ri = rp[1];
        float cr = s0 * rr + s1 * ri;
        float ci = s1 * rr - s0 * ri;
        float f = (kx == 0 || kx == NKX - 1) ? (2.0f / 32400.0f) : (4.0f / 32400.0f);
        Gr[t] = cr * f;
        Gi[t] = ci * f;
    }
    __syncthreads();

    if (t < NY) {
        // T[y=t] = sum_ky G[ky] * exp(+2*pi*i*ky*t/180)
        float ar = 0.f, ai = 0.f;
        int idx = 0;
        for (int ky = 0; ky < NY; ++ky) {
            float c = ctab[idx], s = stab[idx];
            float gr = Gr[ky], gi = Gi[ky];
            ar += gr * c - gi * s;
            ai += gr * s + gi * c;
            idx += t; if (idx >= NY) idx -= NY;
        }
        float* Tp = T + (((size_t)b * NY + (size_t)t) * NKX + (size_t)kx) * 2u;
        Tp[0] = ar; Tp[1] = ai;
    }
}

// Kernel 2: per (b,y) row — kx inverse real DFT + block top-4 candidates.
__global__ __launch_bounds__(256) void k_rowfft_topk(
    const float* __restrict__ T, ull* __restrict__ cand)
{
    const int blk = blockIdx.x;          // b*NY + y
    const int b = blk / NY, y = blk - b * NY;
    const int t = threadIdx.x;

    __shared__ float Trow[2 * NKX];
    __shared__ float ctab[NY], stab[NY];
    __shared__ ull sm[256];

    if (t < NY) {
        double a = (double)t * (6.283185307179586476925286766559 / 180.0);
        ctab[t] = (float)cos(a);
        stab[t] = (float)sin(a);
    }
    {
        const float* Tp = T + ((size_t)(b * NY + y) * NKX) * 2u;
        if (t < 2 * NKX) Trow[t] = Tp[t];
    }
    __syncthreads();

    ull my = 0;
    if (t < NY) {
        float acc = 0.f;
        int idx = 0;
        for (int kx = 0; kx < NKX; ++kx) {
            acc += Trow[2 * kx] * ctab[idx] - Trow[2 * kx + 1] * stab[idx];
            idx += t; if (idx >= NY) idx -= NY;
        }
        int flat = y * NY + t;
        my = ((ull)enc_f(acc) << 32) | (ull)(0x7FFFFFFFu - (unsigned int)flat);
    }

    // 4-round top-4 reduce over the block
    for (int r = 0; r < 4; ++r) {
        sm[t] = my;
        __syncthreads();
        #pragma unroll
        for (int s = 128; s > 0; s >>= 1) {
            if (t < s) { ull o = sm[t + s]; if (o > sm[t]) sm[t] = o; }
            __syncthreads();
        }
        ull win = sm[0];
        if (t == 0) cand[(size_t)blk * 4 + r] = win;
        __syncthreads();
        if (my == win) my = 0;
    }
}

// Kernel 3: per batch — merge 180*4 candidates into final top-4, write outputs.
__global__ __launch_bounds__(256) void k_final(
    const ull* __restrict__ cand, float* __restrict__ out)
{
    const int b = blockIdx.x;
    const int t = threadIdx.x;
    __shared__ ull sm[256];

    ull loc[3];
    #pragma unroll
    for (int k = 0; k < 3; ++k) {
        int i = t + k * 256;
        loc[k] = (i < NY * 4) ? cand[(size_t)b * NY * 4 + i] : 0;
    }

    for (int r = 0; r < 4; ++r) {
        ull m = loc[0];
        if (loc[1] > m) m = loc[1];
        if (loc[2] > m) m = loc[2];
        sm[t] = m;
        __syncthreads();
        #pragma unroll
        for (int s = 128; s > 0; s >>= 1) {
            if (t < s) { ull o = sm[t + s]; if (o > sm[t]) sm[t] = o; }
            __syncthreads();
        }
        ull win = sm[0];
        __syncthreads();
        #pragma unroll
        for (int k = 0; k < 3; ++k) if (loc[k] == win) loc[k] = 0;
        if (t == 0) {
            float val = dec_f((unsigned int)(win >> 32));
            int flat = (int)(0x7FFFFFFFu - (unsigned int)(win & 0xFFFFFFFFu));
            int x = flat % NY, yy = flat / NY;
            out[b * 4 + r] = val;                                  // r_k_val (x2 already folded)
            out[32 + (b * 4 + r) * 2 + 0] = (float)(x - NY / 2);   // trans.x
            out[32 + (b * 4 + r) * 2 + 1] = (float)(yy - NY / 2);  // trans.y
        }
    }
}

extern "C" void kernel_launch(void* const* d_in, const int* in_sizes, int n_in,
                              void* d_out, int out_size, void* d_ws, size_t ws_size,
                              hipStream_t stream) {
    const float* src = (const float*)d_in[0];   // (8,2,192,192,192)
    const float* rot = (const float*)d_in[1];   // (8,1,1,3,3)
    const float* ref = (const float*)d_in[2];   // (8,1,180,91,2)
    // d_in[3] = gridF, recomputed inline
    float* out = (float*)d_out;                 // 32 vals + 64 trans

    // workspace layout
    float* T = (float*)d_ws;                                        // 8*180*91*2 floats = 1,048,320 B
    ull* cand = (ull*)((char*)d_ws + (size_t)NB * NY * NKX * 2 * 4);// 1440*4 u64

    k_sample_colfft<<<dim3(NB * NKX), dim3(192), 0, stream>>>(src, rot, ref, T);
    k_rowfft_topk<<<dim3(NB * NY), dim3(256), 0, stream>>>(T, cand);
    k_final<<<dim3(NB), dim3(256), 0, stream>>>(cand, out);
}

// Round 2
// 521.874 us; speedup vs baseline: 1.0157x; 1.0157x over previous
//
#include <hip/hip_runtime.h>

#define NB 8        // batches
#define NY 180      // render size (ky / y / x count)
#define NKX 91      // rfft half-width
#define NV 192      // volume dim
#define SCALEF (75.0f/16384.0f)   // 180^2/192^3 exactly
#define TWOPI_180 0.034906585039886591538473815369772

typedef unsigned long long ull;

__device__ __forceinline__ unsigned int enc_f(float v) {
    unsigned int u = __float_as_uint(v);
    return (u & 0x80000000u) ? ~u : (u | 0x80000000u);
}
__device__ __forceinline__ float dec_f(unsigned int u) {
    return __uint_as_float((u & 0x80000000u) ? (u & 0x7FFFFFFFu) : ~u);
}
__device__ __forceinline__ ull umax64(ull a, ull b) { return a > b ? a : b; }

// Kernel 1: per (b,kx) column — sample rotated plane, cross-spectrum, ky inverse DFT.
__global__ __launch_bounds__(192) void k_sample_colfft(
    const float* __restrict__ src, const float* __restrict__ rot,
    const float* __restrict__ ref, float* __restrict__ T)
{
    const int blk = blockIdx.x;          // b*NKX + kx
    const int b = blk / NKX, kx = blk - b * NKX;
    const int t = threadIdx.x;

    __shared__ float Gr[NY], Gi[NY];

    if (t < NY) {
        // fftshift: output ky=t comes from sampled row i=(t+90)%180
        int i = t + 90; if (i >= NY) i -= NY;
        float xg = (float)kx / 96.0f;
        float yg = (float)(i - 90) / 96.0f;
        const float* R = rot + (size_t)b * 9;
        float p0 = xg * R[0] + yg * R[3];
        float p1 = xg * R[1] + yg * R[4];
        float p2 = xg * R[2] + yg * R[5];
        float fx = (p0 + 1.0f) * 0.5f * 191.0f;
        float fy = (p1 + 1.0f) * 0.5f * 191.0f;
        float fz = (p2 + 1.0f) * 0.5f * 191.0f;
        float x0 = floorf(fx), y0 = floorf(fy), z0 = floorf(fz);
        float wx = fx - x0, wy = fy - y0, wz = fz - z0;

        // Precompute all 8 taps' offsets+weights, then issue loads together.
        const float* vb = src + (size_t)b * 2u * NV * NV * NV;
        const size_t choff = (size_t)NV * NV * NV;
        float wgt[8];
        size_t off[8];
        bool vld[8];
        #pragma unroll
        for (int k = 0; k < 8; ++k) {
            int dz = k >> 2, dy = (k >> 1) & 1, dx = k & 1;
            float zi = z0 + (float)dz, yi = y0 + (float)dy, xi = x0 + (float)dx;
            vld[k] = (zi >= 0.f) && (zi < (float)NV) && (yi >= 0.f) && (yi < (float)NV)
                  && (xi >= 0.f) && (xi < (float)NV);
            int zc = (int)fminf(fmaxf(zi, 0.f), (float)(NV - 1));
            int yc = (int)fminf(fmaxf(yi, 0.f), (float)(NV - 1));
            int xc = (int)fminf(fmaxf(xi, 0.f), (float)(NV - 1));
            off[k] = ((size_t)zc * NV + (size_t)yc) * NV + (size_t)xc;
            wgt[k] = (dz ? wz : 1.0f - wz) * (dy ? wy : 1.0f - wy) * (dx ? wx : 1.0f - wx);
        }
        float v0[8], v1[8];
        #pragma unroll
        for (int k = 0; k < 8; ++k) {
            v0[k] = vld[k] ? vb[off[k]] : 0.0f;
            v1[k] = vld[k] ? vb[choff + off[k]] : 0.0f;
        }
        float s0 = 0.f, s1 = 0.f;
        #pragma unroll
        for (int k = 0; k < 8; ++k) { s0 += v0[k] * wgt[k]; s1 += v1[k] * wgt[k]; }
        s0 *= SCALEF; s1 *= SCALEF;

        // cross = s * conj(ref);  fold (w_kx * 2 / 180^2)
        const float* rp = ref + (((size_t)b * NY + (size_t)t) * NKX + (size_t)kx) * 2u;
        float rr = rp[0], ri = rp[1];
        float cr = s0 * rr + s1 * ri;
        float ci = s1 * rr - s0 * ri;
        float f = (kx == 0 || kx == NKX - 1) ? (2.0f / 32400.0f) : (4.0f / 32400.0f);
        Gr[t] = cr * f;
        Gi[t] = ci * f;
    }
    __syncthreads();

    if (t < NY) {
        // T[y=t] = sum_ky G[ky] * exp(+2*pi*i*ky*t/180) via rotation recurrence
        double a = (double)t * TWOPI_180;
        float c1 = (float)cos(a), s1 = (float)sin(a);
        float c = 1.0f, s = 0.0f;
        float ar = 0.f, ai = 0.f;
        for (int ky = 0; ky < NY; ++ky) {
            float gr = Gr[ky], gi = Gi[ky];   // loop-uniform → LDS broadcast
            ar += gr * c - gi * s;
            ai += gr * s + gi * c;
            float cn = c * c1 - s * s1;
            s = c * s1 + s * c1;
            c = cn;
        }
        float* Tp = T + (((size_t)b * NY + (size_t)t) * NKX + (size_t)kx) * 2u;
        Tp[0] = ar; Tp[1] = ai;
    }
}

// Kernel 2: per (b,y) row — kx inverse real DFT + block top-4 candidates.
__global__ __launch_bounds__(256) void k_rowfft_topk(
    const float* __restrict__ T, ull* __restrict__ cand)
{
    const int blk = blockIdx.x;          // b*NY + y
    const int b = blk / NY, y = blk - b * NY;
    const int t = threadIdx.x;
    const int lane = t & 63, wid = t >> 6;

    __shared__ float Trow[2 * NKX];
    __shared__ ull sm[8];

    {
        const float* Tp = T + ((size_t)(b * NY + y) * NKX) * 2u;
        if (t < 2 * NKX) Trow[t] = Tp[t];
    }
    __syncthreads();

    ull my = 0;
    if (t < NY) {
        double a = (double)t * TWOPI_180;
        float c1 = (float)cos(a), s1 = (float)sin(a);
        float c = 1.0f, s = 0.0f;
        float acc = 0.f;
        for (int kx = 0; kx < NKX; ++kx) {
            acc += Trow[2 * kx] * c - Trow[2 * kx + 1] * s;  // uniform → broadcast
            float cn = c * c1 - s * s1;
            s = c * s1 + s * c1;
            c = cn;
        }
        int flat = y * NY + t;
        my = ((ull)enc_f(acc) << 32) | (ull)(0x7FFFFFFFu - (unsigned int)flat);
    }

    // 4-round top-4: wave shfl-max (no barrier) + tiny LDS cross-wave merge
    for (int r = 0; r < 4; ++r) {
        ull m = my;
        #pragma unroll
        for (int k = 32; k >= 1; k >>= 1)
            m = umax64(m, (ull)__shfl_xor((long long)m, k));
        if (lane == 0) sm[wid] = m;
        __syncthreads();
        if (t == 0) {
            ull w = sm[0];
            #pragma unroll
            for (int i = 1; i < 4; ++i) w = umax64(w, sm[i]);
            sm[4] = w;
        }
        __syncthreads();
        ull win = sm[4];
        if (t == 0) cand[(size_t)blk * 4 + r] = win;
        if (my == win) my = 0;
    }
}

// Kernel 3: per batch — merge 180*4 candidates into final top-4, write outputs.
__global__ __launch_bounds__(256) void k_final(
    const ull* __restrict__ cand, float* __restrict__ out)
{
    const int b = blockIdx.x;
    const int t = threadIdx.x;
    const int lane = t & 63, wid = t >> 6;
    __shared__ ull sm[8];

    ull loc[3];
    #pragma unroll
    for (int k = 0; k < 3; ++k) {
        int i = t + k * 256;
        loc[k] = (i < NY * 4) ? cand[(size_t)b * NY * 4 + i] : 0;
    }

    for (int r = 0; r < 4; ++r) {
        ull m = umax64(umax64(loc[0], loc[1]), loc[2]);
        #pragma unroll
        for (int k = 32; k >= 1; k >>= 1)
            m = umax64(m, (ull)__shfl_xor((long long)m, k));
        if (lane == 0) sm[wid] = m;
        __syncthreads();
        if (t == 0) {
            ull w = sm[0];
            #pragma unroll
            for (int i = 1; i < 4; ++i) w = umax64(w, sm[i]);
            sm[4] = w;
        }
        __syncthreads();
        ull win = sm[4];
        #pragma unroll
        for (int k = 0; k < 3; ++k) if (loc[k] == win) loc[k] = 0;
        if (t == 0) {
            float val = dec_f((unsigned int)(win >> 32));
            int flat = (int)(0x7FFFFFFFu - (unsigned int)(win & 0xFFFFFFFFu));
            int x = flat % NY, yy = flat / NY;
            out[b * 4 + r] = val;                                  // r_k_val (x2 folded)
            out[32 + (b * 4 + r) * 2 + 0] = (float)(x - NY / 2);   // trans.x
            out[32 + (b * 4 + r) * 2 + 1] = (float)(yy - NY / 2);  // trans.y
        }
        __syncthreads();
    }
}

extern "C" void kernel_launch(void* const* d_in, const int* in_sizes, int n_in,
                              void* d_out, int out_size, void* d_ws, size_t ws_size,
                              hipStream_t stream) {
    const float* src = (const float*)d_in[0];   // (8,2,192,192,192)
    const float* rot = (const float*)d_in[1];   // (8,1,1,3,3)
    const float* ref = (const float*)d_in[2];   // (8,1,180,91,2)
    // d_in[3] = gridF, recomputed inline
    float* out = (float*)d_out;                 // 32 vals + 64 trans

    // workspace layout
    float* T = (float*)d_ws;                                        // 8*180*91*2 floats
    ull* cand = (ull*)((char*)d_ws + (size_t)NB * NY * NKX * 2 * 4);// 1440*4 u64

    k_sample_colfft<<<dim3(NB * NKX), dim3(192), 0, stream>>>(src, rot, ref, T);
    k_rowfft_topk<<<dim3(NB * NY), dim3(256), 0, stream>>>(T, cand);
    k_final<<<dim3(NB), dim3(256), 0, stream>>>(cand, out);
}